// Round 1
// baseline (701.871 us; speedup 1.0000x reference)
//
#include <hip/hip_runtime.h>
#include <hip/hip_bf16.h>
#include <math.h>

#define NBATCH 32
#define IMGSZ  224
#define NR     400
#define NA     1024
#define ED     96
#define H1     80
#define W1     256

// ---------------------------------------------------------------------------
// ws layout (floats unless noted):
//   rtab   [32][400]            12800
//   costab [1024]                1024
//   sintab [1024]                1024
//   w2r    [96][20][96]        184320   (w2 reordered: [oc][p][ic])
//   t1     bf16 [32][80][256][96]       (conv1 output, channels-last)
// total ~126.6 MB
// ---------------------------------------------------------------------------

__global__ void setup_tables_kernel(const float* __restrict__ dist,
                                    float* __restrict__ rtab,
                                    float* __restrict__ costab,
                                    float* __restrict__ sintab,
                                    float* __restrict__ theta_out) {
    const float PI = 3.14159265358979323846f;
    int idx = blockIdx.x * blockDim.x + threadIdx.x;
    if (idx < NBATCH * NR) {
        int b = idx / NR, i = idx % NR;
        float c0 = 0.2f + dist[b*4+0];
        float c1 = 0.2f + dist[b*4+1];
        float c2 = 0.2f + dist[b*4+2];
        float c3 = 0.2f + dist[b*4+3];
        float tmax = 0.5f * PI;
        float t  = tmax * ((float)i + 0.5f) / (float)NR;
        float t2 = t * t;
        float pt = t * (c0 + t2*(c1 + t2*(c2 + t2*c3)));
        float tm2 = tmax * tmax;
        float pm = tmax * (c0 + tm2*(c1 + tm2*(c2 + tm2*c3)));
        rtab[idx] = pt / pm * (0.5f * (float)IMGSZ);
    } else if (idx < NBATCH*NR + NA) {
        int j = idx - NBATCH*NR;
        float phi = 2.0f * PI * ((float)j + 0.5f) / (float)NA;
        costab[j] = cosf(phi);
        sintab[j] = sinf(phi);
    } else if (idx < NBATCH*NR + NA + NBATCH) {
        theta_out[idx - NBATCH*NR - NA] = 0.5f * PI;
    }
}

__global__ void reorder_w2_kernel(const float* __restrict__ w2,
                                  float* __restrict__ w2r) {
    int idx = blockIdx.x * blockDim.x + threadIdx.x;   // [oc][p][ic] order
    if (idx >= ED*ED*20) return;
    int ic = idx % ED;
    int t  = idx / ED;
    int p  = t % 20;
    int oc = t / 20;
    w2r[idx] = w2[(size_t)(oc*ED + ic)*20 + p];
}

// Fused polar bilinear sample + conv1 (patchify GEMM K=60 -> 96).
// One block: (b, r1, 64-wide a1 tile). Samples 5 rows x 256 cols x 3 ch to LDS.
__global__ __launch_bounds__(256)
void sample_conv1_kernel(const float* __restrict__ x,
                         const float* __restrict__ w1,
                         const float* __restrict__ b1,
                         const float* __restrict__ rtab,
                         const float* __restrict__ costab,
                         const float* __restrict__ sintab,
                         __hip_bfloat16* __restrict__ t1) {
    __shared__ float s[3*5*256];   // [c][kr][col]
    __shared__ float w1s[ED*60];   // [oc][k], k=(c*5+kr)*4+ka

    int tid  = threadIdx.x;
    int blk  = blockIdx.x;         // ((b*80 + r1)*4 + tile)
    int tile = blk & 3;
    int tmp  = blk >> 2;
    int r1   = tmp % H1;
    int b    = tmp / H1;

    for (int i = tid; i < ED*60; i += 256) w1s[i] = w1[i];

    // ---- sampling: 5 rows x 256 cols; q-th row handled by all 256 threads
    #pragma unroll
    for (int q = 0; q < 5; ++q) {
        int jglob = tile*256 + tid;
        float r  = rtab[b*NR + r1*5 + q];          // wave-uniform
        float sn = sintab[jglob];
        float cs = costab[jglob];
        // grid[...,0] = y_c/112 -> width coord; grid[...,1] = x_c/112 -> height
        float gx = (r * sn * (1.0f/112.0f) + 1.0f) * (0.5f * 223.0f);
        float gy = (r * cs * (1.0f/112.0f) + 1.0f) * (0.5f * 223.0f);
        float x0f = floorf(gx), y0f = floorf(gy);
        float wx1 = gx - x0f, wx0 = 1.0f - wx1;
        float wy1 = gy - y0f, wy0 = 1.0f - wy1;
        int ix = (int)x0f, iy = (int)y0f;
        // mathematically always in [0,222]; clamp only as a segfault guard
        ix = min(max(ix, 0), IMGSZ-2);
        iy = min(max(iy, 0), IMGSZ-2);
        const float* img = x + (size_t)b*3*IMGSZ*IMGSZ + iy*IMGSZ + ix;
        #pragma unroll
        for (int c = 0; c < 3; ++c) {
            const float* pc = img + c*IMGSZ*IMGSZ;
            float v00 = pc[0], v01 = pc[1];
            float v10 = pc[IMGSZ], v11 = pc[IMGSZ+1];
            s[(c*5 + q)*256 + tid] =
                wy0*(wx0*v00 + wx1*v01) + wy1*(wx0*v10 + wx1*v11);
        }
    }
    __syncthreads();

    // ---- conv1: 64 pixels x 96 oc, per-thread 4x6 register tile
    int tn = tid & 15;     // oc group: oc = io*16 + tn
    int ta = tid >> 4;     // pixel group: a_local = ta*4 + ia
    float acc[4][6];
    #pragma unroll
    for (int io = 0; io < 6; ++io) {
        float bias = b1[io*16 + tn];
        #pragma unroll
        for (int ia = 0; ia < 4; ++ia) acc[ia][io] = bias;
    }
    #pragma unroll
    for (int ck = 0; ck < 15; ++ck) {          // ck = c*5+kr; inner 4 = ka
        float4 a4[4];
        #pragma unroll
        for (int ia = 0; ia < 4; ++ia)
            a4[ia] = *(const float4*)&s[ck*256 + (ta*4 + ia)*4];
        #pragma unroll
        for (int io = 0; io < 6; ++io) {
            float4 w4 = *(const float4*)&w1s[(io*16 + tn)*60 + ck*4];
            #pragma unroll
            for (int ia = 0; ia < 4; ++ia)
                acc[ia][io] += a4[ia].x*w4.x + a4[ia].y*w4.y
                             + a4[ia].z*w4.z + a4[ia].w*w4.w;
        }
    }
    // store t1[b][r1][a1][oc] as bf16
    size_t base = (((size_t)b*H1 + r1)*W1 + tile*64)*ED;
    #pragma unroll
    for (int ia = 0; ia < 4; ++ia)
        #pragma unroll
        for (int io = 0; io < 6; ++io)
            t1[base + (size_t)(ta*4 + ia)*ED + io*16 + tn] =
                __float2bfloat16(acc[ia][io]);
}

// conv2 as GEMM: M = 64 pixels (one b,r2 row), N = 96, K = 1920 (20 p x 96 ic)
__global__ __launch_bounds__(256)
void conv2_kernel(const __hip_bfloat16* __restrict__ t1,
                  const float* __restrict__ w2r,
                  const float* __restrict__ b2,
                  float* __restrict__ out) {
    __shared__ float s_a[64*100];  // [a2][ic], pad 100 -> 2-way max (free)
    __shared__ float s_b[96*100];  // [oc][ic]

    int tid = threadIdx.x;
    int blk = blockIdx.x;          // b*16 + r2
    int r2  = blk & 15;
    int b   = blk >> 4;
    int tn  = tid & 15;            // oc = io*16 + tn
    int ta  = tid >> 4;            // a2 = ta*4 + ia

    float acc[4][6];
    #pragma unroll
    for (int io = 0; io < 6; ++io) {
        float bias = b2[io*16 + tn];
        #pragma unroll
        for (int ia = 0; ia < 4; ++ia) acc[ia][io] = bias;
    }

    for (int p = 0; p < 20; ++p) {
        int kr = p >> 2, ka = p & 3;
        int r1 = r2*5 + kr;
        // A chunk: 64 pixels x 96 ic (bf16 -> fp32)
        for (int idx = tid; idx < 64*ED; idx += 256) {
            int a2l = idx / ED;
            int ic  = idx - a2l*ED;
            int a1  = a2l*4 + ka;
            s_a[a2l*100 + ic] =
                __bfloat162float(t1[(((size_t)b*H1 + r1)*W1 + a1)*ED + ic]);
        }
        // B chunk: 96 oc x 96 ic
        for (int idx = tid; idx < ED*ED; idx += 256) {
            int oc = idx / ED;
            int ic = idx - oc*ED;
            s_b[oc*100 + ic] = w2r[(size_t)(oc*20 + p)*ED + ic];
        }
        __syncthreads();
        #pragma unroll
        for (int k = 0; k < ED; k += 4) {
            float4 a4[4], w4[6];
            #pragma unroll
            for (int ia = 0; ia < 4; ++ia)
                a4[ia] = *(const float4*)&s_a[(ta*4 + ia)*100 + k];
            #pragma unroll
            for (int io = 0; io < 6; ++io)
                w4[io] = *(const float4*)&s_b[(io*16 + tn)*100 + k];
            #pragma unroll
            for (int ia = 0; ia < 4; ++ia)
                #pragma unroll
                for (int io = 0; io < 6; ++io)
                    acc[ia][io] += a4[ia].x*w4[io].x + a4[ia].y*w4[io].y
                                 + a4[ia].z*w4[io].z + a4[ia].w*w4[io].w;
        }
        __syncthreads();
    }
    // out[b][s][oc], s = r2*64 + a2
    size_t base = ((size_t)b*1024 + r2*64)*ED;
    #pragma unroll
    for (int ia = 0; ia < 4; ++ia)
        #pragma unroll
        for (int io = 0; io < 6; ++io)
            out[base + (size_t)(ta*4 + ia)*ED + io*16 + tn] = acc[ia][io];
}

extern "C" void kernel_launch(void* const* d_in, const int* in_sizes, int n_in,
                              void* d_out, int out_size, void* d_ws, size_t ws_size,
                              hipStream_t stream) {
    const float* x    = (const float*)d_in[0];
    const float* dist = (const float*)d_in[1];
    const float* w1   = (const float*)d_in[2];
    const float* b1   = (const float*)d_in[3];
    const float* w2   = (const float*)d_in[4];
    const float* b2   = (const float*)d_in[5];
    float* out = (float*)d_out;

    float* rtab   = (float*)d_ws;                 // 12800
    float* costab = rtab + NBATCH*NR;             // 1024
    float* sintab = costab + NA;                  // 1024
    float* w2r    = sintab + NA;                  // 184320
    __hip_bfloat16* t1 = (__hip_bfloat16*)(w2r + ED*ED*20);

    float* theta_out = out + (size_t)NBATCH*1024*ED;

    setup_tables_kernel<<<(NBATCH*NR + NA + NBATCH + 255)/256, 256, 0, stream>>>(
        dist, rtab, costab, sintab, theta_out);
    reorder_w2_kernel<<<(ED*ED*20 + 255)/256, 256, 0, stream>>>(w2, w2r);
    sample_conv1_kernel<<<NBATCH*H1*4, 256, 0, stream>>>(
        x, w1, b1, rtab, costab, sintab, t1);
    conv2_kernel<<<NBATCH*16, 256, 0, stream>>>(t1, w2r, b2, out);
}

// Round 2
// 291.683 us; speedup vs baseline: 2.4063x; 2.4063x over previous
//
#include <hip/hip_runtime.h>
#include <hip/hip_bf16.h>
#include <math.h>

#define NBATCH 32
#define IMGSZ  224
#define NR     400
#define NA     1024
#define ED     96
#define H1     80
#define W1     256

typedef __bf16 bf16x8 __attribute__((ext_vector_type(8)));
typedef float  f32x4  __attribute__((ext_vector_type(4)));

// ---------------------------------------------------------------------------
// ws layout:
//   rtab   f32 [32][400]          12800 elems
//   costab f32 [1024]
//   sintab f32 [1024]
//   w2r    bf16 [96][20][96]     184320 elems  (w2 reordered [oc][p][ic])
//   t1     bf16 [32][80][256][96]               (conv1 out, channels-last)
// ---------------------------------------------------------------------------

__global__ void setup_tables_kernel(const float* __restrict__ dist,
                                    float* __restrict__ rtab,
                                    float* __restrict__ costab,
                                    float* __restrict__ sintab,
                                    float* __restrict__ theta_out) {
    const float PI = 3.14159265358979323846f;
    int idx = blockIdx.x * blockDim.x + threadIdx.x;
    if (idx < NBATCH * NR) {
        int b = idx / NR, i = idx % NR;
        float c0 = 0.2f + dist[b*4+0];
        float c1 = 0.2f + dist[b*4+1];
        float c2 = 0.2f + dist[b*4+2];
        float c3 = 0.2f + dist[b*4+3];
        float tmax = 0.5f * PI;
        float t  = tmax * ((float)i + 0.5f) / (float)NR;
        float t2 = t * t;
        float pt = t * (c0 + t2*(c1 + t2*(c2 + t2*c3)));
        float tm2 = tmax * tmax;
        float pm = tmax * (c0 + tm2*(c1 + tm2*(c2 + tm2*c3)));
        rtab[idx] = pt / pm * (0.5f * (float)IMGSZ);
    } else if (idx < NBATCH*NR + NA) {
        int j = idx - NBATCH*NR;
        float phi = 2.0f * PI * ((float)j + 0.5f) / (float)NA;
        costab[j] = cosf(phi);
        sintab[j] = sinf(phi);
    } else if (idx < NBATCH*NR + NA + NBATCH) {
        theta_out[idx - NBATCH*NR - NA] = 0.5f * PI;
    }
}

// w2 fp32 [oc][ic][5][4] -> w2r bf16 [oc][p][ic], p = kr*4+ka
__global__ void reorder_w2_kernel(const float* __restrict__ w2,
                                  __bf16* __restrict__ w2r) {
    int idx = blockIdx.x * blockDim.x + threadIdx.x;
    if (idx >= ED*ED*20) return;
    int ic = idx % ED;
    int t  = idx / ED;
    int p  = t % 20;
    int oc = t / 20;
    w2r[idx] = (__bf16)w2[(size_t)(oc*ED + ic)*20 + p];
}

// Fused polar bilinear sample + conv1 (patchify GEMM K=60 -> 96).
__global__ __launch_bounds__(256)
void sample_conv1_kernel(const float* __restrict__ x,
                         const float* __restrict__ w1,
                         const float* __restrict__ b1,
                         const float* __restrict__ rtab,
                         const float* __restrict__ costab,
                         const float* __restrict__ sintab,
                         __hip_bfloat16* __restrict__ t1) {
    __shared__ float s[3*5*256];   // [c][kr][col]
    __shared__ float w1s[ED*60];   // [oc][k], k=(c*5+kr)*4+ka

    int tid  = threadIdx.x;
    int blk  = blockIdx.x;         // ((b*80 + r1)*4 + tile)
    int tile = blk & 3;
    int tmp  = blk >> 2;
    int r1   = tmp % H1;
    int b    = tmp / H1;

    for (int i = tid; i < ED*60; i += 256) w1s[i] = w1[i];

    #pragma unroll
    for (int q = 0; q < 5; ++q) {
        int jglob = tile*256 + tid;
        float r  = rtab[b*NR + r1*5 + q];
        float sn = sintab[jglob];
        float cs = costab[jglob];
        float gx = (r * sn * (1.0f/112.0f) + 1.0f) * (0.5f * 223.0f);
        float gy = (r * cs * (1.0f/112.0f) + 1.0f) * (0.5f * 223.0f);
        float x0f = floorf(gx), y0f = floorf(gy);
        float wx1 = gx - x0f, wx0 = 1.0f - wx1;
        float wy1 = gy - y0f, wy0 = 1.0f - wy1;
        int ix = (int)x0f, iy = (int)y0f;
        ix = min(max(ix, 0), IMGSZ-2);
        iy = min(max(iy, 0), IMGSZ-2);
        const float* img = x + (size_t)b*3*IMGSZ*IMGSZ + iy*IMGSZ + ix;
        #pragma unroll
        for (int c = 0; c < 3; ++c) {
            const float* pc = img + c*IMGSZ*IMGSZ;
            float v00 = pc[0], v01 = pc[1];
            float v10 = pc[IMGSZ], v11 = pc[IMGSZ+1];
            s[(c*5 + q)*256 + tid] =
                wy0*(wx0*v00 + wx1*v01) + wy1*(wx0*v10 + wx1*v11);
        }
    }
    __syncthreads();

    int tn = tid & 15;
    int ta = tid >> 4;
    float acc[4][6];
    #pragma unroll
    for (int io = 0; io < 6; ++io) {
        float bias = b1[io*16 + tn];
        #pragma unroll
        for (int ia = 0; ia < 4; ++ia) acc[ia][io] = bias;
    }
    #pragma unroll
    for (int ck = 0; ck < 15; ++ck) {
        float4 a4[4];
        #pragma unroll
        for (int ia = 0; ia < 4; ++ia)
            a4[ia] = *(const float4*)&s[ck*256 + (ta*4 + ia)*4];
        #pragma unroll
        for (int io = 0; io < 6; ++io) {
            float4 w4 = *(const float4*)&w1s[(io*16 + tn)*60 + ck*4];
            #pragma unroll
            for (int ia = 0; ia < 4; ++ia)
                acc[ia][io] += a4[ia].x*w4.x + a4[ia].y*w4.y
                             + a4[ia].z*w4.z + a4[ia].w*w4.w;
        }
    }
    size_t base = (((size_t)b*H1 + r1)*W1 + tile*64)*ED;
    #pragma unroll
    for (int ia = 0; ia < 4; ++ia)
        #pragma unroll
        for (int io = 0; io < 6; ++io)
            t1[base + (size_t)(ta*4 + ia)*ED + io*16 + tn] =
                __float2bfloat16(acc[ia][io]);
}

// conv2 as bf16 MFMA GEMM: D[m][oc] = sum_k t1_patch[m][k] * w2r[oc][k]
// M = 32768 (b,r2,a2), N = 96, K = 1920 (p=kr*4+ka times ic=96).
// Per wave: one 16-row m-tile x full N (6 n-tiles). Block = 4 waves = M 64.
__global__ __launch_bounds__(256)
void conv2_mfma_kernel(const __bf16* __restrict__ t1,
                       const __bf16* __restrict__ w2r,
                       const float* __restrict__ b2,
                       float* __restrict__ out) {
    int tid  = threadIdx.x;
    int wave = tid >> 6;
    int lane = tid & 63;
    int l15  = lane & 15;
    int quad = lane >> 4;

    int m0  = blockIdx.x * 64 + wave * 16;   // m-tile base
    int b   = m0 >> 10;
    int r2  = (m0 >> 6) & 15;
    int a2b = m0 & 63;                        // 0,16,32,48

    f32x4 acc[6];
    #pragma unroll
    for (int nt = 0; nt < 6; ++nt) acc[nt] = (f32x4){0.f, 0.f, 0.f, 0.f};

    // A-fragment: lane reads t1[b][r2*5+kr][(a2b+l15)*4+ka][ic0+quad*8 .. +7]
    const __bf16* tbase = t1 + ((size_t)b*H1)*W1*ED;

    #pragma unroll 2
    for (int p = 0; p < 20; ++p) {
        int kr = p >> 2, ka = p & 3;
        const __bf16* arow = tbase + ((size_t)(r2*5 + kr)*W1
                                      + (a2b + l15)*4 + ka)*ED + quad*8;
        const __bf16* brow = w2r + (size_t)l15*20*ED + (size_t)p*ED + quad*8;
        #pragma unroll
        for (int icb = 0; icb < 3; ++icb) {
            bf16x8 af = *(const bf16x8*)(arow + icb*32);
            #pragma unroll
            for (int nt = 0; nt < 6; ++nt) {
                bf16x8 bf = *(const bf16x8*)(brow + (size_t)nt*16*20*ED + icb*32);
                acc[nt] = __builtin_amdgcn_mfma_f32_16x16x32_bf16(af, bf, acc[nt], 0, 0, 0);
            }
        }
    }

    // C/D layout: col(oc) = l15, row(m) = quad*4 + reg
    #pragma unroll
    for (int nt = 0; nt < 6; ++nt) {
        int oc = nt*16 + l15;
        float bias = b2[oc];
        #pragma unroll
        for (int r = 0; r < 4; ++r) {
            int m = m0 + quad*4 + r;
            out[(size_t)m*ED + oc] = acc[nt][r] + bias;
        }
    }
}

extern "C" void kernel_launch(void* const* d_in, const int* in_sizes, int n_in,
                              void* d_out, int out_size, void* d_ws, size_t ws_size,
                              hipStream_t stream) {
    const float* x    = (const float*)d_in[0];
    const float* dist = (const float*)d_in[1];
    const float* w1   = (const float*)d_in[2];
    const float* b1   = (const float*)d_in[3];
    const float* w2   = (const float*)d_in[4];
    const float* b2   = (const float*)d_in[5];
    float* out = (float*)d_out;

    float* rtab   = (float*)d_ws;                 // 12800
    float* costab = rtab + NBATCH*NR;             // 1024
    float* sintab = costab + NA;                  // 1024
    __bf16* w2r   = (__bf16*)(sintab + NA);       // 184320 bf16
    __hip_bfloat16* t1 = (__hip_bfloat16*)(w2r + ED*ED*20);

    float* theta_out = out + (size_t)NBATCH*1024*ED;

    setup_tables_kernel<<<(NBATCH*NR + NA + NBATCH + 255)/256, 256, 0, stream>>>(
        dist, rtab, costab, sintab, theta_out);
    reorder_w2_kernel<<<(ED*ED*20 + 255)/256, 256, 0, stream>>>(w2, w2r);
    sample_conv1_kernel<<<NBATCH*H1*4, 256, 0, stream>>>(
        x, w1, b1, rtab, costab, sintab, t1);
    conv2_mfma_kernel<<<NBATCH*1024/64, 256, 0, stream>>>(
        (const __bf16*)t1, w2r, b2, out);
}

// Round 3
// 284.246 us; speedup vs baseline: 2.4692x; 1.0262x over previous
//
#include <hip/hip_runtime.h>
#include <hip/hip_bf16.h>
#include <math.h>

#define NBATCH 32
#define IMGSZ  224
#define NR     400
#define NA     1024
#define ED     96
#define H1     80
#define W1     256

typedef __bf16 bf16x8 __attribute__((ext_vector_type(8)));
typedef float  f32x4  __attribute__((ext_vector_type(4)));

// ---------------------------------------------------------------------------
// ws layout:
//   rtab   f32 [32][400]          12800 elems
//   costab f32 [1024]
//   sintab f32 [1024]
//   w2r    bf16 [96][20][96]     184320 elems  (w2 reordered [oc][p][ic])
//   w1r    bf16 [96][64]           6144 elems  (w1 flat [oc][k], k 60..63 = 0)
//   t1     bf16 [32][80][256][96]               (conv1 out, channels-last)
// ---------------------------------------------------------------------------

__global__ void setup_tables_kernel(const float* __restrict__ dist,
                                    float* __restrict__ rtab,
                                    float* __restrict__ costab,
                                    float* __restrict__ sintab,
                                    float* __restrict__ theta_out) {
    const float PI = 3.14159265358979323846f;
    int idx = blockIdx.x * blockDim.x + threadIdx.x;
    if (idx < NBATCH * NR) {
        int b = idx / NR, i = idx % NR;
        float c0 = 0.2f + dist[b*4+0];
        float c1 = 0.2f + dist[b*4+1];
        float c2 = 0.2f + dist[b*4+2];
        float c3 = 0.2f + dist[b*4+3];
        float tmax = 0.5f * PI;
        float t  = tmax * ((float)i + 0.5f) / (float)NR;
        float t2 = t * t;
        float pt = t * (c0 + t2*(c1 + t2*(c2 + t2*c3)));
        float tm2 = tmax * tmax;
        float pm = tmax * (c0 + tm2*(c1 + tm2*(c2 + tm2*c3)));
        rtab[idx] = pt / pm * (0.5f * (float)IMGSZ);
    } else if (idx < NBATCH*NR + NA) {
        int j = idx - NBATCH*NR;
        float phi = 2.0f * PI * ((float)j + 0.5f) / (float)NA;
        costab[j] = cosf(phi);
        sintab[j] = sinf(phi);
    } else if (idx < NBATCH*NR + NA + NBATCH) {
        theta_out[idx - NBATCH*NR - NA] = 0.5f * PI;
    }
}

// w2 fp32 [oc][ic][5][4] -> w2r bf16 [oc][p][ic];  w1 fp32 [oc][60] -> w1r bf16 [oc][64]
__global__ void reorder_weights_kernel(const float* __restrict__ w2,
                                       const float* __restrict__ w1,
                                       __bf16* __restrict__ w2r,
                                       __bf16* __restrict__ w1r) {
    int idx = blockIdx.x * blockDim.x + threadIdx.x;
    if (idx < ED*ED*20) {
        int ic = idx % ED;
        int t  = idx / ED;
        int p  = t % 20;
        int oc = t / 20;
        w2r[idx] = (__bf16)w2[(size_t)(oc*ED + ic)*20 + p];
    } else if (idx < ED*ED*20 + ED*64) {
        int i2 = idx - ED*ED*20;
        int oc = i2 >> 6, k = i2 & 63;
        w1r[i2] = (k < 60) ? (__bf16)w1[oc*60 + k] : (__bf16)0.0f;
    }
}

// pack 8 fp32 -> bf16x8 (round-half-away via +0x8000 then truncate hi16)
static __device__ inline bf16x8 pack_bf16x8(f32x4 lo, f32x4 hi) {
    union { f32x4 v; unsigned int u[4]; } a, b;
    a.v = lo; b.v = hi;
    union { bf16x8 v; unsigned int u[4]; } r;
    unsigned int a0 = a.u[0] + 0x8000u, a1 = a.u[1] + 0x8000u;
    unsigned int a2 = a.u[2] + 0x8000u, a3 = a.u[3] + 0x8000u;
    unsigned int b0 = b.u[0] + 0x8000u, b1 = b.u[1] + 0x8000u;
    unsigned int b2 = b.u[2] + 0x8000u, b3 = b.u[3] + 0x8000u;
    r.u[0] = __builtin_amdgcn_perm(a1, a0, 0x07060302u);  // {lo.x,lo.y}
    r.u[1] = __builtin_amdgcn_perm(a3, a2, 0x07060302u);  // {lo.z,lo.w}
    r.u[2] = __builtin_amdgcn_perm(b1, b0, 0x07060302u);  // {hi.x,hi.y}
    r.u[3] = __builtin_amdgcn_perm(b3, b2, 0x07060302u);  // {hi.z,hi.w}
    return r.v;
}

// Fused polar bilinear sample + conv1 as bf16 MFMA patchify GEMM.
// Block: (b, r1, 64-pixel tile). Samples 5 rows x 256 cols x 3 ch to LDS fp32,
// then 4 waves each do a 16m x 96n x K64 MFMA GEMM from LDS fragments.
__global__ __launch_bounds__(256)
void sample_conv1_mfma(const float* __restrict__ x,
                       const __bf16* __restrict__ w1r,
                       const float* __restrict__ b1,
                       const float* __restrict__ rtab,
                       const float* __restrict__ costab,
                       const float* __restrict__ sintab,
                       __hip_bfloat16* __restrict__ t1) {
    __shared__ float s[16*264];    // [ck][col], ck=c*5+kr (15 used, row15=0), pad 264

    int tid  = threadIdx.x;
    int blk  = blockIdx.x;         // ((b*80 + r1)*4 + tile)
    int tile = blk & 3;
    int tmp  = blk >> 2;
    int r1   = tmp % H1;
    int b    = tmp / H1;

    // zero pad row ck=15 (k = 60..63)
    for (int i = tid; i < 264; i += 256) s[15*264 + i] = 0.0f;

    // ---- sampling: 5 radius rows x 256 azimuth cols x 3 channels
    #pragma unroll
    for (int q = 0; q < 5; ++q) {
        int jglob = tile*256 + tid;
        float r  = rtab[b*NR + r1*5 + q];          // wave-uniform
        float sn = sintab[jglob];
        float cs = costab[jglob];
        float gx = (r * sn * (1.0f/112.0f) + 1.0f) * (0.5f * 223.0f);
        float gy = (r * cs * (1.0f/112.0f) + 1.0f) * (0.5f * 223.0f);
        float x0f = floorf(gx), y0f = floorf(gy);
        float wx1 = gx - x0f, wx0 = 1.0f - wx1;
        float wy1 = gy - y0f, wy0 = 1.0f - wy1;
        int ix = (int)x0f, iy = (int)y0f;
        ix = min(max(ix, 0), IMGSZ-2);             // always in-bounds; guard only
        iy = min(max(iy, 0), IMGSZ-2);
        const float* img = x + (size_t)b*3*IMGSZ*IMGSZ + iy*IMGSZ + ix;
        #pragma unroll
        for (int c = 0; c < 3; ++c) {
            const float* pc = img + c*IMGSZ*IMGSZ;
            float v00 = pc[0], v01 = pc[1];
            float v10 = pc[IMGSZ], v11 = pc[IMGSZ+1];
            s[(c*5 + q)*264 + tid] =
                wy0*(wx0*v00 + wx1*v01) + wy1*(wx0*v10 + wx1*v11);
        }
    }

    // ---- B fragments (block-invariant): w1r[oc][64], B[n=l15][k=quad*8+j]
    int wave = tid >> 6;
    int lane = tid & 63;
    int l15  = lane & 15;
    int quad = lane >> 4;

    bf16x8 bfrag[2][6];
    #pragma unroll
    for (int ks = 0; ks < 2; ++ks)
        #pragma unroll
        for (int nt = 0; nt < 6; ++nt)
            bfrag[ks][nt] = *(const bf16x8*)(w1r + (nt*16 + l15)*64 + ks*32 + quad*8);

    __syncthreads();

    // ---- MFMA: wave handles pixels m = wave*16 + l15 (local), k = ks*32+quad*8+j
    f32x4 acc[6];
    #pragma unroll
    for (int nt = 0; nt < 6; ++nt) acc[nt] = (f32x4){0.f, 0.f, 0.f, 0.f};

    int colb = (wave*16 + l15)*4;   // col = m_local*4 + ka
    #pragma unroll
    for (int ks = 0; ks < 2; ++ks) {
        int ck0 = ks*8 + quad*2;
        f32x4 lo = *(const f32x4*)&s[ck0*264 + colb];
        f32x4 hi = *(const f32x4*)&s[(ck0+1)*264 + colb];
        bf16x8 af = pack_bf16x8(lo, hi);
        #pragma unroll
        for (int nt = 0; nt < 6; ++nt)
            acc[nt] = __builtin_amdgcn_mfma_f32_16x16x32_bf16(af, bfrag[ks][nt], acc[nt], 0, 0, 0);
    }

    // ---- epilogue: C col=l15 (oc), row=quad*4+r (pixel); add bias, store bf16
    size_t base = (((size_t)b*H1 + r1)*W1 + tile*64 + wave*16)*ED;
    #pragma unroll
    for (int nt = 0; nt < 6; ++nt) {
        int oc = nt*16 + l15;
        float bias = b1[oc];
        #pragma unroll
        for (int r = 0; r < 4; ++r)
            t1[base + (size_t)(quad*4 + r)*ED + oc] =
                __float2bfloat16(acc[nt][r] + bias);
    }
}

// conv2 as bf16 MFMA GEMM: D[m][oc] = sum_k t1_patch[m][k] * w2r[oc][k]
__global__ __launch_bounds__(256)
void conv2_mfma_kernel(const __bf16* __restrict__ t1,
                       const __bf16* __restrict__ w2r,
                       const float* __restrict__ b2,
                       float* __restrict__ out) {
    int tid  = threadIdx.x;
    int wave = tid >> 6;
    int lane = tid & 63;
    int l15  = lane & 15;
    int quad = lane >> 4;

    int m0  = blockIdx.x * 64 + wave * 16;   // m-tile base
    int b   = m0 >> 10;
    int r2  = (m0 >> 6) & 15;
    int a2b = m0 & 63;

    f32x4 acc[6];
    #pragma unroll
    for (int nt = 0; nt < 6; ++nt) acc[nt] = (f32x4){0.f, 0.f, 0.f, 0.f};

    const __bf16* tbase = t1 + ((size_t)b*H1)*W1*ED;

    #pragma unroll 2
    for (int p = 0; p < 20; ++p) {
        int kr = p >> 2, ka = p & 3;
        const __bf16* arow = tbase + ((size_t)(r2*5 + kr)*W1
                                      + (a2b + l15)*4 + ka)*ED + quad*8;
        const __bf16* brow = w2r + (size_t)l15*20*ED + (size_t)p*ED + quad*8;
        #pragma unroll
        for (int icb = 0; icb < 3; ++icb) {
            bf16x8 af = *(const bf16x8*)(arow + icb*32);
            #pragma unroll
            for (int nt = 0; nt < 6; ++nt) {
                bf16x8 bf = *(const bf16x8*)(brow + (size_t)nt*16*20*ED + icb*32);
                acc[nt] = __builtin_amdgcn_mfma_f32_16x16x32_bf16(af, bf, acc[nt], 0, 0, 0);
            }
        }
    }

    #pragma unroll
    for (int nt = 0; nt < 6; ++nt) {
        int oc = nt*16 + l15;
        float bias = b2[oc];
        #pragma unroll
        for (int r = 0; r < 4; ++r) {
            int m = m0 + quad*4 + r;
            out[(size_t)m*ED + oc] = acc[nt][r] + bias;
        }
    }
}

extern "C" void kernel_launch(void* const* d_in, const int* in_sizes, int n_in,
                              void* d_out, int out_size, void* d_ws, size_t ws_size,
                              hipStream_t stream) {
    const float* x    = (const float*)d_in[0];
    const float* dist = (const float*)d_in[1];
    const float* w1   = (const float*)d_in[2];
    const float* b1   = (const float*)d_in[3];
    const float* w2   = (const float*)d_in[4];
    const float* b2   = (const float*)d_in[5];
    float* out = (float*)d_out;

    float* rtab   = (float*)d_ws;                 // 12800
    float* costab = rtab + NBATCH*NR;             // 1024
    float* sintab = costab + NA;                  // 1024
    __bf16* w2r   = (__bf16*)(sintab + NA);       // 184320 bf16
    __bf16* w1r   = w2r + ED*ED*20;               // 6144 bf16
    __hip_bfloat16* t1 = (__hip_bfloat16*)(w1r + ED*64);

    float* theta_out = out + (size_t)NBATCH*1024*ED;

    setup_tables_kernel<<<(NBATCH*NR + NA + NBATCH + 255)/256, 256, 0, stream>>>(
        dist, rtab, costab, sintab, theta_out);
    reorder_weights_kernel<<<(ED*ED*20 + ED*64 + 255)/256, 256, 0, stream>>>(
        w2, w1, w2r, w1r);
    sample_conv1_mfma<<<NBATCH*H1*4, 256, 0, stream>>>(
        x, w1r, b1, rtab, costab, sintab, t1);
    conv2_mfma_kernel<<<NBATCH*1024/64, 256, 0, stream>>>(
        (const __bf16*)t1, w2r, b2, out);
}

// Round 4
// 221.545 us; speedup vs baseline: 3.1681x; 1.2830x over previous
//
#include <hip/hip_runtime.h>
#include <hip/hip_bf16.h>
#include <math.h>

#define NBATCH 32
#define IMGSZ  224
#define NR     400
#define NA     1024
#define ED     96
#define H1     80
#define W1     256

typedef __attribute__((ext_vector_type(8))) __bf16 bf16x8;
typedef __attribute__((ext_vector_type(8), aligned(8))) __bf16 bf16x8u; // 16B load @8B align
typedef __attribute__((ext_vector_type(4))) __bf16 bf16x4;
typedef __attribute__((ext_vector_type(4))) float f32x4;

// ---------------------------------------------------------------------------
// ws layout:
//   rtab   f32 [32][400]                12800
//   costab f32 [1024]
//   sintab f32 [1024]
//   w2f    bf16 [20*3*6][64][8]        184320  (fragment-major w2)
//   w1r    bf16 [96][64]                 6144
//   xp     bf16 [32][224][224][4]     6422528  (channels-last packed image)
//   t1     bf16 [32][80][256][96]              (conv1 out, channels-last)
// total ~139 MB
// ---------------------------------------------------------------------------

__global__ void setup_tables_kernel(const float* __restrict__ dist,
                                    float* __restrict__ rtab,
                                    float* __restrict__ costab,
                                    float* __restrict__ sintab,
                                    float* __restrict__ theta_out) {
    const float PI = 3.14159265358979323846f;
    int idx = blockIdx.x * blockDim.x + threadIdx.x;
    if (idx < NBATCH * NR) {
        int b = idx / NR, i = idx % NR;
        float c0 = 0.2f + dist[b*4+0];
        float c1 = 0.2f + dist[b*4+1];
        float c2 = 0.2f + dist[b*4+2];
        float c3 = 0.2f + dist[b*4+3];
        float tmax = 0.5f * PI;
        float t  = tmax * ((float)i + 0.5f) / (float)NR;
        float t2 = t * t;
        float pt = t * (c0 + t2*(c1 + t2*(c2 + t2*c3)));
        float tm2 = tmax * tmax;
        float pm = tmax * (c0 + tm2*(c1 + tm2*(c2 + tm2*c3)));
        rtab[idx] = pt / pm * (0.5f * (float)IMGSZ);
    } else if (idx < NBATCH*NR + NA) {
        int j = idx - NBATCH*NR;
        float phi = 2.0f * PI * ((float)j + 0.5f) / (float)NA;
        costab[j] = cosf(phi);
        sintab[j] = sinf(phi);
    } else if (idx < NBATCH*NR + NA + NBATCH) {
        theta_out[idx - NBATCH*NR - NA] = 0.5f * PI;
    }
}

// w2 fp32 [oc][ic][5][4] -> w2f bf16 fragment-major: [(p*3+icb)*6+nt][lane][j]
//   oc = nt*16 + (lane&15), ic = icb*32 + (lane>>4)*8 + j
// w1 fp32 [oc][60] -> w1r bf16 [oc][64] (k 60..63 zero)
__global__ void reorder_weights_kernel(const float* __restrict__ w2,
                                       const float* __restrict__ w1,
                                       __bf16* __restrict__ w2f,
                                       __bf16* __restrict__ w1r) {
    int idx = blockIdx.x * blockDim.x + threadIdx.x;
    if (idx < ED*ED*20) {
        int j    = idx & 7;
        int lane = (idx >> 3) & 63;
        int grp  = idx >> 9;            // (p*3+icb)*6 + nt
        int nt   = grp % 6;
        int t    = grp / 6;
        int icb  = t % 3;
        int p    = t / 3;
        int oc = nt*16 + (lane & 15);
        int ic = icb*32 + (lane >> 4)*8 + j;
        w2f[idx] = (__bf16)w2[((size_t)(oc*ED + ic)*5 + (p >> 2))*4 + (p & 3)];
    } else if (idx < ED*ED*20 + ED*64) {
        int i2 = idx - ED*ED*20;
        int oc = i2 >> 6, k = i2 & 63;
        w1r[i2] = (k < 60) ? (__bf16)w1[oc*60 + k] : (__bf16)0.0f;
    }
}

// x fp32 [b][c][y][x] -> xp bf16 [b][y][x][4] (c0,c1,c2,0)
__global__ __launch_bounds__(256)
void pack_image_kernel(const float* __restrict__ x, __bf16* __restrict__ xp) {
    int idx = blockIdx.x * 256 + threadIdx.x;
    if (idx >= NBATCH*IMGSZ*IMGSZ) return;
    int b  = idx / (IMGSZ*IMGSZ);
    int px = idx - b*(IMGSZ*IMGSZ);
    const float* p = x + (size_t)b*3*IMGSZ*IMGSZ + px;
    bf16x4 o;
    o[0] = (__bf16)p[0];
    o[1] = (__bf16)p[IMGSZ*IMGSZ];
    o[2] = (__bf16)p[2*IMGSZ*IMGSZ];
    o[3] = (__bf16)0.0f;
    *(bf16x4*)(xp + (size_t)idx*4) = o;
}

// pack 8 fp32 -> bf16x8
static __device__ inline bf16x8 pack_bf16x8(f32x4 lo, f32x4 hi) {
    union { f32x4 v; unsigned int u[4]; } a, b;
    a.v = lo; b.v = hi;
    union { bf16x8 v; unsigned int u[4]; } r;
    unsigned int a0 = a.u[0] + 0x8000u, a1 = a.u[1] + 0x8000u;
    unsigned int a2 = a.u[2] + 0x8000u, a3 = a.u[3] + 0x8000u;
    unsigned int b0 = b.u[0] + 0x8000u, b1 = b.u[1] + 0x8000u;
    unsigned int b2 = b.u[2] + 0x8000u, b3 = b.u[3] + 0x8000u;
    r.u[0] = __builtin_amdgcn_perm(a1, a0, 0x07060302u);
    r.u[1] = __builtin_amdgcn_perm(a3, a2, 0x07060302u);
    r.u[2] = __builtin_amdgcn_perm(b1, b0, 0x07060302u);
    r.u[3] = __builtin_amdgcn_perm(b3, b2, 0x07060302u);
    return r.v;
}

// Fused polar bilinear sample + conv1 as bf16 MFMA patchify GEMM.
__global__ __launch_bounds__(256)
void sample_conv1_mfma(const __bf16* __restrict__ xp,
                       const __bf16* __restrict__ w1r,
                       const float* __restrict__ b1,
                       const float* __restrict__ rtab,
                       const float* __restrict__ costab,
                       const float* __restrict__ sintab,
                       __hip_bfloat16* __restrict__ t1) {
    __shared__ float s[16*264];    // [ck][col], ck=c*5+kr (row 15 = zero pad)

    int tid  = threadIdx.x;
    int blk  = blockIdx.x;         // ((b*80 + r1)*4 + tile)
    int tile = blk & 3;
    int tmp  = blk >> 2;
    int r1   = tmp % H1;
    int b    = tmp / H1;

    for (int i = tid; i < 264; i += 256) s[15*264 + i] = 0.0f;

    // ---- sampling: one 16-B load per corner-row fetches both x-corners x 3ch
    #pragma unroll
    for (int q = 0; q < 5; ++q) {
        int jglob = tile*256 + tid;
        float r  = rtab[b*NR + r1*5 + q];          // wave-uniform
        float sn = sintab[jglob];
        float cs = costab[jglob];
        float gx = (r * sn * (1.0f/112.0f) + 1.0f) * (0.5f * 223.0f);
        float gy = (r * cs * (1.0f/112.0f) + 1.0f) * (0.5f * 223.0f);
        float x0f = floorf(gx), y0f = floorf(gy);
        float wx1 = gx - x0f, wx0 = 1.0f - wx1;
        float wy1 = gy - y0f, wy0 = 1.0f - wy1;
        int ix = (int)x0f, iy = (int)y0f;
        ix = min(max(ix, 0), IMGSZ-2);             // always in-bounds; guard only
        iy = min(max(iy, 0), IMGSZ-2);
        const __bf16* img = xp + ((size_t)(b*IMGSZ + iy)*IMGSZ + ix)*4;
        bf16x8u p0 = *(const bf16x8u*)img;          // (iy, ix), (iy, ix+1)
        bf16x8u p1 = *(const bf16x8u*)(img + IMGSZ*4);
        float w00 = wy0*wx0, w01 = wy0*wx1, w10 = wy1*wx0, w11 = wy1*wx1;
        #pragma unroll
        for (int c = 0; c < 3; ++c) {
            s[(c*5 + q)*264 + tid] =
                w00*(float)p0[c] + w01*(float)p0[4+c]
              + w10*(float)p1[c] + w11*(float)p1[4+c];
        }
    }

    // ---- B fragments (block-invariant)
    int wave = tid >> 6;
    int lane = tid & 63;
    int l15  = lane & 15;
    int quad = lane >> 4;

    bf16x8 bfrag[2][6];
    #pragma unroll
    for (int ks = 0; ks < 2; ++ks)
        #pragma unroll
        for (int nt = 0; nt < 6; ++nt)
            bfrag[ks][nt] = *(const bf16x8*)(w1r + (nt*16 + l15)*64 + ks*32 + quad*8);

    __syncthreads();

    f32x4 acc[6];
    #pragma unroll
    for (int nt = 0; nt < 6; ++nt) acc[nt] = (f32x4){0.f, 0.f, 0.f, 0.f};

    int colb = (wave*16 + l15)*4;
    #pragma unroll
    for (int ks = 0; ks < 2; ++ks) {
        int ck0 = ks*8 + quad*2;
        f32x4 lo = *(const f32x4*)&s[ck0*264 + colb];
        f32x4 hi = *(const f32x4*)&s[(ck0+1)*264 + colb];
        bf16x8 af = pack_bf16x8(lo, hi);
        #pragma unroll
        for (int nt = 0; nt < 6; ++nt)
            acc[nt] = __builtin_amdgcn_mfma_f32_16x16x32_bf16(af, bfrag[ks][nt], acc[nt], 0, 0, 0);
    }

    size_t base = (((size_t)b*H1 + r1)*W1 + tile*64 + wave*16)*ED;
    #pragma unroll
    for (int nt = 0; nt < 6; ++nt) {
        int oc = nt*16 + l15;
        float bias = b1[oc];
        #pragma unroll
        for (int r = 0; r < 4; ++r)
            t1[base + (size_t)(quad*4 + r)*ED + oc] =
                __float2bfloat16(acc[nt][r] + bias);
    }
}

// conv2 bf16 MFMA GEMM; B from fragment-major w2f (coalesced 16B/lane loads)
__global__ __launch_bounds__(256)
void conv2_mfma_kernel(const __bf16* __restrict__ t1,
                       const __bf16* __restrict__ w2f,
                       const float* __restrict__ b2,
                       float* __restrict__ out) {
    int tid  = threadIdx.x;
    int wave = tid >> 6;
    int lane = tid & 63;
    int l15  = lane & 15;
    int quad = lane >> 4;

    int m0  = blockIdx.x * 64 + wave * 16;
    int b   = m0 >> 10;
    int r2  = (m0 >> 6) & 15;
    int a2b = m0 & 63;

    f32x4 acc[6];
    #pragma unroll
    for (int nt = 0; nt < 6; ++nt) acc[nt] = (f32x4){0.f, 0.f, 0.f, 0.f};

    const __bf16* tbase = t1 + ((size_t)b*H1)*W1*ED;

    #pragma unroll 2
    for (int p = 0; p < 20; ++p) {
        int kr = p >> 2, ka = p & 3;
        const __bf16* arow = tbase + ((size_t)(r2*5 + kr)*W1
                                      + (a2b + l15)*4 + ka)*ED + quad*8;
        #pragma unroll
        for (int icb = 0; icb < 3; ++icb) {
            bf16x8 af = *(const bf16x8*)(arow + icb*32);
            const __bf16* wp = w2f + (size_t)((p*3 + icb)*6)*512 + lane*8;
            #pragma unroll
            for (int nt = 0; nt < 6; ++nt) {
                bf16x8 bf = *(const bf16x8*)(wp + nt*512);
                acc[nt] = __builtin_amdgcn_mfma_f32_16x16x32_bf16(af, bf, acc[nt], 0, 0, 0);
            }
        }
    }

    #pragma unroll
    for (int nt = 0; nt < 6; ++nt) {
        int oc = nt*16 + l15;
        float bias = b2[oc];
        #pragma unroll
        for (int r = 0; r < 4; ++r) {
            int m = m0 + quad*4 + r;
            out[(size_t)m*ED + oc] = acc[nt][r] + bias;
        }
    }
}

extern "C" void kernel_launch(void* const* d_in, const int* in_sizes, int n_in,
                              void* d_out, int out_size, void* d_ws, size_t ws_size,
                              hipStream_t stream) {
    const float* x    = (const float*)d_in[0];
    const float* dist = (const float*)d_in[1];
    const float* w1   = (const float*)d_in[2];
    const float* b1   = (const float*)d_in[3];
    const float* w2   = (const float*)d_in[4];
    const float* b2   = (const float*)d_in[5];
    float* out = (float*)d_out;

    float* rtab   = (float*)d_ws;                 // 12800
    float* costab = rtab + NBATCH*NR;             // 1024
    float* sintab = costab + NA;                  // 1024
    __bf16* w2f   = (__bf16*)(sintab + NA);       // 184320 bf16
    __bf16* w1r   = w2f + ED*ED*20;               // 6144 bf16
    __bf16* xp    = w1r + ED*64;                  // 32*224*224*4 bf16
    __hip_bfloat16* t1 = (__hip_bfloat16*)(xp + (size_t)NBATCH*IMGSZ*IMGSZ*4);

    float* theta_out = out + (size_t)NBATCH*1024*ED;

    setup_tables_kernel<<<(NBATCH*NR + NA + NBATCH + 255)/256, 256, 0, stream>>>(
        dist, rtab, costab, sintab, theta_out);
    reorder_weights_kernel<<<(ED*ED*20 + ED*64 + 255)/256, 256, 0, stream>>>(
        w2, w1, w2f, w1r);
    pack_image_kernel<<<(NBATCH*IMGSZ*IMGSZ + 255)/256, 256, 0, stream>>>(x, xp);
    sample_conv1_mfma<<<NBATCH*H1*4, 256, 0, stream>>>(
        xp, w1r, b1, rtab, costab, sintab, t1);
    conv2_mfma_kernel<<<NBATCH*1024/64, 256, 0, stream>>>(
        (const __bf16*)t1, w2f, b2, out);
}

// Round 5
// 210.939 us; speedup vs baseline: 3.3274x; 1.0503x over previous
//
#include <hip/hip_runtime.h>
#include <hip/hip_bf16.h>
#include <math.h>

#define NBATCH 32
#define IMGSZ  224
#define NR     400
#define NA     1024
#define ED     96
#define SROW   516   // s_samp padded row length (512 cols + 4)

typedef __attribute__((ext_vector_type(8))) __bf16 bf16x8;
typedef __attribute__((ext_vector_type(8), aligned(8))) __bf16 bf16x8u;
typedef __attribute__((ext_vector_type(4), aligned(8))) __bf16 bf16x4a;
typedef __attribute__((ext_vector_type(4))) __bf16 bf16x4;
typedef __attribute__((ext_vector_type(4))) float f32x4;

union frag_u { struct { bf16x4a lo, hi; } p; bf16x8 v; };

// ---------------------------------------------------------------------------
// ws layout:
//   rtab    f32 [32][400]
//   costab  f32 [1024]   (pre-scaled by 223/224)
//   sintab  f32 [1024]   (pre-scaled by 223/224)
//   w2f     bf16 [20*3*6][64][8]   fragment-major w2
//   w1r     bf16 [96][64]          w1 flat, k 60..63 = 0
//   xp      bf16 [32][224][224][4] channels-last packed image
// ---------------------------------------------------------------------------

__global__ void setup_tables_kernel(const float* __restrict__ dist,
                                    float* __restrict__ rtab,
                                    float* __restrict__ costab,
                                    float* __restrict__ sintab,
                                    float* __restrict__ theta_out) {
    const float PI = 3.14159265358979323846f;
    const float SC = 223.0f / 224.0f;
    int idx = blockIdx.x * blockDim.x + threadIdx.x;
    if (idx < NBATCH * NR) {
        int b = idx / NR, i = idx % NR;
        float c0 = 0.2f + dist[b*4+0];
        float c1 = 0.2f + dist[b*4+1];
        float c2 = 0.2f + dist[b*4+2];
        float c3 = 0.2f + dist[b*4+3];
        float tmax = 0.5f * PI;
        float t  = tmax * ((float)i + 0.5f) / (float)NR;
        float t2 = t * t;
        float pt = t * (c0 + t2*(c1 + t2*(c2 + t2*c3)));
        float tm2 = tmax * tmax;
        float pm = tmax * (c0 + tm2*(c1 + tm2*(c2 + tm2*c3)));
        rtab[idx] = pt / pm * (0.5f * (float)IMGSZ);
    } else if (idx < NBATCH*NR + NA) {
        int j = idx - NBATCH*NR;
        float phi = 2.0f * PI * ((float)j + 0.5f) / (float)NA;
        costab[j] = cosf(phi) * SC;
        sintab[j] = sinf(phi) * SC;
    } else if (idx < NBATCH*NR + NA + NBATCH) {
        theta_out[idx - NBATCH*NR - NA] = 0.5f * PI;
    }
}

// w2 fp32 [oc][ic][5][4] -> w2f bf16 fragment-major: [(p*3+icb)*6+nt][lane][j]
//   oc = nt*16 + (lane&15), ic = icb*32 + (lane>>4)*8 + j, p = kr'*4+ka'
// w1 fp32 [oc][60] -> w1r bf16 [oc][64] (k 60..63 zero)
__global__ void reorder_weights_kernel(const float* __restrict__ w2,
                                       const float* __restrict__ w1,
                                       __bf16* __restrict__ w2f,
                                       __bf16* __restrict__ w1r) {
    int idx = blockIdx.x * blockDim.x + threadIdx.x;
    if (idx < ED*ED*20) {
        int j    = idx & 7;
        int lane = (idx >> 3) & 63;
        int grp  = idx >> 9;            // (p*3+icb)*6 + nt
        int nt   = grp % 6;
        int t    = grp / 6;
        int icb  = t % 3;
        int p    = t / 3;
        int oc = nt*16 + (lane & 15);
        int ic = icb*32 + (lane >> 4)*8 + j;
        w2f[idx] = (__bf16)w2[((size_t)(oc*ED + ic)*5 + (p >> 2))*4 + (p & 3)];
    } else if (idx < ED*ED*20 + ED*64) {
        int i2 = idx - ED*ED*20;
        int oc = i2 >> 6, k = i2 & 63;
        w1r[i2] = (k < 60) ? (__bf16)w1[oc*60 + k] : (__bf16)0.0f;
    }
}

// x fp32 [b][c][y][x] -> xp bf16 [b][y][x][4] (c0,c1,c2,0)
__global__ __launch_bounds__(256)
void pack_image_kernel(const float* __restrict__ x, __bf16* __restrict__ xp) {
    int idx = blockIdx.x * 256 + threadIdx.x;
    if (idx >= NBATCH*IMGSZ*IMGSZ) return;
    int b  = idx / (IMGSZ*IMGSZ);
    int px = idx - b*(IMGSZ*IMGSZ);
    const float* p = x + (size_t)b*3*IMGSZ*IMGSZ + px;
    bf16x4 o;
    o[0] = (__bf16)p[0];
    o[1] = (__bf16)p[IMGSZ*IMGSZ];
    o[2] = (__bf16)p[2*IMGSZ*IMGSZ];
    o[3] = (__bf16)0.0f;
    *(bf16x4*)(xp + (size_t)idx*4) = o;
}

// ---------------------------------------------------------------------------
// Fully fused: polar sample -> conv1 (MFMA, D[oc][pixel]) -> LDS fragment
// relayout -> conv2 (MFMA, register-accumulated over kr) -> out.
// Block = (b, r2, azimuth half ah). 256 threads = 4 waves.
//   per kr in 0..4:  sample 5x512 grid pts -> s_samp (bf16)
//                    conv1': 8 pixel-tiles (2/wave), write t1f fragment-major
//                    conv2 partial: wave (mt = w>>1, khalf = w&1), 6 k-steps
//   end: cross-wave k-half reduction via LDS, add biases, store.
// ---------------------------------------------------------------------------
__global__ __launch_bounds__(256)
void fused_kernel(const __bf16* __restrict__ xp,
                  const __bf16* __restrict__ w1r,
                  const __bf16* __restrict__ w2f,
                  const float* __restrict__ b1,
                  const float* __restrict__ b2,
                  const float* __restrict__ rtab,
                  const float* __restrict__ costab,
                  const float* __restrict__ sintab,
                  float* __restrict__ out) {
    __shared__ __bf16 t1f[12*32*4*8];                 // 24576 B
    __shared__ __attribute__((aligned(16))) __bf16 s_samp[15*SROW]; // 15480 B

    int tid = threadIdx.x;
    int bid = blockIdx.x;
    int g   = bid >> 8;                  // 0..3
    int r2  = (bid & 15) ^ g;            // scramble radius band across CUs
    int m4  = (bid >> 4) & 15;
    int ah  = m4 & 1;
    int b   = g*8 + (m4 >> 1);

    int wave = tid >> 6, lane = tid & 63, l15 = lane & 15, quad = lane >> 4;
    int mt = wave >> 1, kp = wave & 1;

    // conv1 weight fragments (A operand: m = oc): w1r[oc][k]
    bf16x8 wfrag[2][6];
    #pragma unroll
    for (int ks = 0; ks < 2; ++ks)
        #pragma unroll
        for (int ot = 0; ot < 6; ++ot)
            wfrag[ks][ot] = *(const bf16x8*)(w1r + (ot*16 + l15)*64 + ks*32 + quad*8);

    // conv1 bias: lane's oc rows = ot*16 + quad*4 + r
    f32x4 b1v[6];
    #pragma unroll
    for (int ot = 0; ot < 6; ++ot)
        b1v[ot] = *(const f32x4*)(b1 + ot*16 + quad*4);

    f32x4 acc2[6];
    #pragma unroll
    for (int nt = 0; nt < 6; ++nt) acc2[nt] = (f32x4){0.f,0.f,0.f,0.f};

    const __bf16* xpb = xp + (size_t)b*IMGSZ*IMGSZ*4;
    int rbase = b*NR + r2*25;

    for (int kr = 0; kr < 5; ++kr) {
        // ---- sampling: 5 q-rows x 512 azimuth cols x 3 ch -> s_samp bf16
        #pragma unroll
        for (int q = 0; q < 5; ++q) {
            float r = rtab[rbase + kr*5 + q];          // block-uniform
            #pragma unroll
            for (int ch = 0; ch < 2; ++ch) {
                int col = ch*256 + tid;
                int az  = ah*512 + col;
                float sn = sintab[az];
                float cs = costab[az];
                float gx = fmaf(r, sn, 111.5f);
                float gy = fmaf(r, cs, 111.5f);
                float x0f = floorf(gx), y0f = floorf(gy);
                float wx1 = gx - x0f, wx0 = 1.0f - wx1;
                float wy1 = gy - y0f, wy0 = 1.0f - wy1;
                int ix = (int)x0f, iy = (int)y0f;
                ix = min(max(ix, 0), IMGSZ-2);         // guard only
                iy = min(max(iy, 0), IMGSZ-2);
                const __bf16* img = xpb + ((size_t)iy*IMGSZ + ix)*4;
                bf16x8u p0 = *(const bf16x8u*)img;
                bf16x8u p1 = *(const bf16x8u*)(img + IMGSZ*4);
                float w00 = wy0*wx0, w01 = wy0*wx1, w10 = wy1*wx0, w11 = wy1*wx1;
                #pragma unroll
                for (int c = 0; c < 3; ++c) {
                    float v = w00*(float)p0[c] + w01*(float)p0[4+c]
                            + w10*(float)p1[c] + w11*(float)p1[4+c];
                    s_samp[(c*5 + q)*SROW + col] = (__bf16)v;
                }
            }
        }
        __syncthreads();   // A: samples ready (also fences prev-kr t1f reads)

        // ---- conv1': D[oc][pixel]; wave handles pixel-tiles wave*2, wave*2+1
        #pragma unroll
        for (int i = 0; i < 2; ++i) {
            int pt = wave*2 + i;
            int colb = (pt*16 + l15)*4;   // this lane's pixel column base
            f32x4 acc1[6];
            #pragma unroll
            for (int ot = 0; ot < 6; ++ot) acc1[ot] = (f32x4){0.f,0.f,0.f,0.f};

            {   // ks = 0 : k 0..31, rows ck0 = quad*2, quad*2+1
                int ck0 = quad*2;
                frag_u f;
                f.p.lo = *(const bf16x4a*)&s_samp[ck0*SROW + colb];
                f.p.hi = *(const bf16x4a*)&s_samp[(ck0+1)*SROW + colb];
                #pragma unroll
                for (int ot = 0; ot < 6; ++ot)
                    acc1[ot] = __builtin_amdgcn_mfma_f32_16x16x32_bf16(
                        wfrag[0][ot], f.v, acc1[ot], 0, 0, 0);
            }
            {   // ks = 1 : k 32..63, rows 8+quad*2, 9+quad*2 (row 15 = zeros)
                int ck0 = 8 + quad*2;
                frag_u f;
                f.p.lo = *(const bf16x4a*)&s_samp[ck0*SROW + colb];
                if (quad == 3) {
                    f.p.hi = (bf16x4a){};
                } else {
                    f.p.hi = *(const bf16x4a*)&s_samp[(ck0+1)*SROW + colb];
                }
                #pragma unroll
                for (int ot = 0; ot < 6; ++ot)
                    acc1[ot] = __builtin_amdgcn_mfma_f32_16x16x32_bf16(
                        wfrag[1][ot], f.v, acc1[ot], 0, 0, 0);
            }

            // epilogue: lane holds pixel = pt*16+l15, oc = ot*16+quad*4+r
            // -> t1f fragment-major [kk(ka,icb)][a2l][quad2][j], one b64/ot
            int pixel = pt*16 + l15;
            int a2l = pixel >> 2, ka = pixel & 3;
            #pragma unroll
            for (int ot = 0; ot < 6; ++ot) {
                f32x4 v = acc1[ot] + b1v[ot];
                bf16x4a w;
                w[0] = (__bf16)v[0]; w[1] = (__bf16)v[1];
                w[2] = (__bf16)v[2]; w[3] = (__bf16)v[3];
                int icbase = ot*16 + quad*4;
                int icb = icbase >> 5;
                int q2  = (icbase >> 3) & 3;
                int jb  = icbase & 7;
                *(bf16x4a*)&t1f[(((ka*3 + icb)*32 + a2l)*4 + q2)*8 + jb] = w;
            }
        }
        __syncthreads();   // B: t1f row ready (cross-wave)

        // ---- conv2 partial for this kr: wave's k-half = 6 k-steps
        #pragma unroll
        for (int ki = 0; ki < 6; ++ki) {
            int ka  = kp*2 + ki/3;       // kp half: ka in {0,1} or {2,3}
            int icb = ki % 3;
            int kk  = (ka*3 + icb);
            int p   = kr*4 + ka;
            bf16x8 af = *(const bf16x8*)&t1f[((kk*32 + mt*16 + l15)*4 + quad)*8];
            const __bf16* wp = w2f + (size_t)((p*3 + icb)*6)*512 + lane*8;
            #pragma unroll
            for (int nt = 0; nt < 6; ++nt) {
                bf16x8 bf = *(const bf16x8*)(wp + nt*512);
                acc2[nt] = __builtin_amdgcn_mfma_f32_16x16x32_bf16(af, bf, acc2[nt], 0, 0, 0);
            }
        }
        // no barrier: next iteration's barrier A fences t1f reuse
    }

    // ---- k-half reduction (red aliases s_samp; all s_samp reads complete)
    float* red = (float*)s_samp;         // [mt][row 16][97] fp32, 12416 B
    if (kp) {
        #pragma unroll
        for (int nt = 0; nt < 6; ++nt)
            #pragma unroll
            for (int r = 0; r < 4; ++r)
                red[mt*1552 + (quad*4 + r)*97 + nt*16 + l15] = acc2[nt][r];
    }
    __syncthreads();
    if (!kp) {
        size_t ob = ((size_t)b*1024 + r2*64 + ah*32 + mt*16)*ED;
        #pragma unroll
        for (int nt = 0; nt < 6; ++nt) {
            int oc = nt*16 + l15;
            float bias = b2[oc];
            #pragma unroll
            for (int r = 0; r < 4; ++r) {
                float v = acc2[nt][r] + red[mt*1552 + (quad*4 + r)*97 + oc] + bias;
                out[ob + (size_t)(quad*4 + r)*ED + oc] = v;
            }
        }
    }
}

extern "C" void kernel_launch(void* const* d_in, const int* in_sizes, int n_in,
                              void* d_out, int out_size, void* d_ws, size_t ws_size,
                              hipStream_t stream) {
    const float* x    = (const float*)d_in[0];
    const float* dist = (const float*)d_in[1];
    const float* w1   = (const float*)d_in[2];
    const float* b1   = (const float*)d_in[3];
    const float* w2   = (const float*)d_in[4];
    const float* b2   = (const float*)d_in[5];
    float* out = (float*)d_out;

    float* rtab   = (float*)d_ws;                 // 12800
    float* costab = rtab + NBATCH*NR;             // 1024
    float* sintab = costab + NA;                  // 1024
    __bf16* w2f   = (__bf16*)(sintab + NA);       // 184320 bf16
    __bf16* w1r   = w2f + ED*ED*20;               // 6144 bf16
    __bf16* xp    = w1r + ED*64;                  // 32*224*224*4 bf16

    float* theta_out = out + (size_t)NBATCH*1024*ED;

    setup_tables_kernel<<<(NBATCH*NR + NA + NBATCH + 255)/256, 256, 0, stream>>>(
        dist, rtab, costab, sintab, theta_out);
    reorder_weights_kernel<<<(ED*ED*20 + ED*64 + 255)/256, 256, 0, stream>>>(
        w2, w1, w2f, w1r);
    pack_image_kernel<<<(NBATCH*IMGSZ*IMGSZ + 255)/256, 256, 0, stream>>>(x, xp);
    fused_kernel<<<NBATCH*16*2, 256, 0, stream>>>(
        xp, w1r, w2f, b1, b2, rtab, costab, sintab, out);
}

// Round 6
// 187.465 us; speedup vs baseline: 3.7440x; 1.1252x over previous
//
#include <hip/hip_runtime.h>
#include <hip/hip_bf16.h>
#include <math.h>

#define NBATCH 32
#define IMGSZ  224
#define NR     400
#define NA     1024
#define ED     96
#define SROWE  520   // s_samp row length in elems (512 cols + 8 pad)

typedef __attribute__((ext_vector_type(8))) __bf16 bf16x8;
typedef __attribute__((ext_vector_type(8), aligned(8))) __bf16 bf16x8u;
typedef __attribute__((ext_vector_type(4), aligned(8))) __bf16 bf16x4a;
typedef __attribute__((ext_vector_type(4))) __bf16 bf16x4;
typedef __attribute__((ext_vector_type(4))) float f32x4;

union frag_u { struct { bf16x4a lo, hi; } p; bf16x8 v; };
union bpack  { __bf16 h[2]; unsigned u; };

// ---------------------------------------------------------------------------
// ws layout:
//   rtab    f32 [32][400]
//   costab  f32 [1024]   (pre-scaled by 223/224)
//   sintab  f32 [1024]   (pre-scaled by 223/224)
//   w2f     bf16 [20*3*6][64][8]     fragment-major w2
//   w1r     bf16 [96][64]            w1 flat, k 60..63 = 0
//   xp      bf16 [32][224][224][4]   channels-last packed image
//   sp      bf16 [32][3][400][1024]  sampled polar planes (az contiguous)
// ---------------------------------------------------------------------------

// merged: distortion tables + theta output + weight reorder
__global__ __launch_bounds__(256)
void prep_kernel(const float* __restrict__ dist,
                 const float* __restrict__ w1,
                 const float* __restrict__ w2,
                 float* __restrict__ rtab,
                 float* __restrict__ costab,
                 float* __restrict__ sintab,
                 __bf16* __restrict__ w2f,
                 __bf16* __restrict__ w1r,
                 float* __restrict__ theta_out) {
    const float PI = 3.14159265358979323846f;
    const float SC = 223.0f / 224.0f;
    int idx = blockIdx.x * 256 + threadIdx.x;

    // ---- tables
    if (idx < NBATCH * NR) {
        int b = idx / NR, i = idx % NR;
        float c0 = 0.2f + dist[b*4+0];
        float c1 = 0.2f + dist[b*4+1];
        float c2 = 0.2f + dist[b*4+2];
        float c3 = 0.2f + dist[b*4+3];
        float tmax = 0.5f * PI;
        float t  = tmax * ((float)i + 0.5f) / (float)NR;
        float t2 = t * t;
        float pt = t * (c0 + t2*(c1 + t2*(c2 + t2*c3)));
        float tm2 = tmax * tmax;
        float pm = tmax * (c0 + tm2*(c1 + tm2*(c2 + tm2*c3)));
        rtab[idx] = pt / pm * (0.5f * (float)IMGSZ);
    } else if (idx < NBATCH*NR + NA) {
        int j = idx - NBATCH*NR;
        float phi = 2.0f * PI * ((float)j + 0.5f) / (float)NA;
        costab[j] = cosf(phi) * SC;
        sintab[j] = sinf(phi) * SC;
    } else if (idx < NBATCH*NR + NA + NBATCH) {
        theta_out[idx - NBATCH*NR - NA] = 0.5f * PI;
    }

    // ---- weights
    if (idx < ED*ED*20) {
        // w2f fragment-major: [(p*3+icb)*6+nt][lane][j]
        int j    = idx & 7;
        int lane = (idx >> 3) & 63;
        int grp  = idx >> 9;
        int nt   = grp % 6;
        int t    = grp / 6;
        int icb  = t % 3;
        int p    = t / 3;
        int oc = nt*16 + (lane & 15);
        int ic = icb*32 + (lane >> 4)*8 + j;
        w2f[idx] = (__bf16)w2[((size_t)(oc*ED + ic)*5 + (p >> 2))*4 + (p & 3)];
    } else if (idx < ED*ED*20 + ED*64) {
        int i2 = idx - ED*ED*20;
        int oc = i2 >> 6, k = i2 & 63;
        w1r[i2] = (k < 60) ? (__bf16)w1[oc*60 + k] : (__bf16)0.0f;
    }
}

// x fp32 [b][c][y][x] -> xp bf16 [b][y][x][4] (c0,c1,c2,0)
__global__ __launch_bounds__(256)
void pack_image_kernel(const float* __restrict__ x, __bf16* __restrict__ xp) {
    int idx = blockIdx.x * 256 + threadIdx.x;
    if (idx >= NBATCH*IMGSZ*IMGSZ) return;
    int b  = idx / (IMGSZ*IMGSZ);
    int px = idx - b*(IMGSZ*IMGSZ);
    const float* p = x + (size_t)b*3*IMGSZ*IMGSZ + px;
    bf16x4 o;
    o[0] = (__bf16)p[0];
    o[1] = (__bf16)p[IMGSZ*IMGSZ];
    o[2] = (__bf16)p[2*IMGSZ*IMGSZ];
    o[3] = (__bf16)0.0f;
    *(bf16x4*)(xp + (size_t)idx*4) = o;
}

// ---------------------------------------------------------------------------
// Polar bilinear gather, locality-tiled: wave = 8 radius x 16 azimuth tile,
// thread = 2 azimuth-adjacent points. No LDS, no barriers; latency hidden
// by massive occupancy. Output planar: sp[((b*3+c)*NR + r)*NA + az].
// ---------------------------------------------------------------------------
__global__ __launch_bounds__(256)
void sample_kernel(const __bf16* __restrict__ xp,
                   const float* __restrict__ rtab,
                   const float* __restrict__ costab,
                   const float* __restrict__ sintab,
                   __bf16* __restrict__ sp) {
    int tid = threadIdx.x;
    int at = blockIdx.x, rt = blockIdx.y, b = blockIdx.z;
    int w = tid >> 6, lane = tid & 63;
    int dr = lane >> 3, dag = lane & 7;
    int r  = rt*16 + (w & 1)*8 + dr;
    int az = at*32 + (w >> 1)*16 + dag*2;

    float rv = rtab[b*NR + r];
    const __bf16* xpb = xp + (size_t)b*IMGSZ*IMGSZ*4;

    float res[2][3];
    #pragma unroll
    for (int i = 0; i < 2; ++i) {
        float sn = sintab[az + i];
        float cs = costab[az + i];
        float gx = fmaf(rv, sn, 111.5f);   // width  coord (= yc in ref grid)
        float gy = fmaf(rv, cs, 111.5f);   // height coord
        float x0f = floorf(gx), y0f = floorf(gy);
        float wx1 = gx - x0f, wx0 = 1.0f - wx1;
        float wy1 = gy - y0f, wy0 = 1.0f - wy1;
        int ix = (int)x0f, iy = (int)y0f;
        ix = min(max(ix, 0), IMGSZ-2);     // always in-bounds; guard only
        iy = min(max(iy, 0), IMGSZ-2);
        const __bf16* img = xpb + ((size_t)iy*IMGSZ + ix)*4;
        bf16x8u p0 = *(const bf16x8u*)img;
        bf16x8u p1 = *(const bf16x8u*)(img + IMGSZ*4);
        float w00 = wy0*wx0, w01 = wy0*wx1, w10 = wy1*wx0, w11 = wy1*wx1;
        #pragma unroll
        for (int c = 0; c < 3; ++c)
            res[i][c] = w00*(float)p0[c] + w01*(float)p0[4+c]
                      + w10*(float)p1[c] + w11*(float)p1[4+c];
    }
    #pragma unroll
    for (int c = 0; c < 3; ++c) {
        bpack pk;
        pk.h[0] = (__bf16)res[0][c];
        pk.h[1] = (__bf16)res[1][c];
        *(unsigned*)(sp + ((size_t)(b*3 + c)*NR + r)*NA + az) = pk.u;
    }
}

// ---------------------------------------------------------------------------
// conv1 (MFMA, D[oc][pixel]) -> LDS fragment relayout -> conv2 (MFMA,
// register-accumulated over kr). Sampled rows staged LDS-direct via
// global_load_lds width=16, prefetched for kr+1 during conv2.
// Block = (b, r2, azimuth half). 256 threads = 4 waves.
// ---------------------------------------------------------------------------
__global__ __launch_bounds__(256, 4)
void conv_fused_kernel(const __bf16* __restrict__ sp,
                       const __bf16* __restrict__ w1r,
                       const __bf16* __restrict__ w2f,
                       const float* __restrict__ b1,
                       const float* __restrict__ b2,
                       float* __restrict__ out) {
    __shared__ __bf16 t1f[12*32*4*8];                               // 24576 B
    __shared__ __attribute__((aligned(16))) __bf16 s_samp[15*SROWE]; // 15600 B

    int tid = threadIdx.x;
    int bid = blockIdx.x;
    int g   = bid >> 8;                  // 0..3
    int r2  = (bid & 15) ^ g;            // scramble radius band across CUs
    int m4  = (bid >> 4) & 15;
    int ah  = m4 & 1;
    int b   = g*8 + (m4 >> 1);

    int wave = tid >> 6, lane = tid & 63, l15 = lane & 15, quad = lane >> 4;
    int mt = wave >> 1, kp = wave & 1;

    // conv1 weight fragments (A operand: m = oc)
    bf16x8 wfrag[2][6];
    #pragma unroll
    for (int ks = 0; ks < 2; ++ks)
        #pragma unroll
        for (int ot = 0; ot < 6; ++ot)
            wfrag[ks][ot] = *(const bf16x8*)(w1r + (ot*16 + l15)*64 + ks*32 + quad*8);

    f32x4 b1v[6];
    #pragma unroll
    for (int ot = 0; ot < 6; ++ot)
        b1v[ot] = *(const f32x4*)(b1 + ot*16 + quad*4);

    f32x4 acc2[6];
    #pragma unroll
    for (int nt = 0; nt < 6; ++nt) acc2[nt] = (f32x4){0.f,0.f,0.f,0.f};

    // staging: row ck = c*5+q <- sp[(b*3+c)*NR + r2*25 + kr*5 + q][ah*512..]
    const __bf16* spb = sp + (size_t)(b*3)*NR*NA + (size_t)ah*512 + lane*8;
    int rr = r2*25;

    auto stage = [&](int kr) {
        for (int ck = wave; ck < 15; ck += 4) {          // ck wave-uniform
            int c = ck / 5, q = ck - c*5;
            const __bf16* gp = spb + (size_t)(c*NR + rr + kr*5 + q)*NA;
            __builtin_amdgcn_global_load_lds(
                (const __attribute__((address_space(1))) void*)gp,
                (__attribute__((address_space(3))) void*)&s_samp[ck*SROWE],
                16, 0, 0);
        }
    };

    stage(0);

    for (int kr = 0; kr < 5; ++kr) {
        __syncthreads();   // A: staged rows visible; prev-kr t1f reads done

        // ---- conv1': D[oc][pixel]; wave handles pixel-tiles wave*2, wave*2+1
        #pragma unroll
        for (int i = 0; i < 2; ++i) {
            int pt = wave*2 + i;
            int colb = (pt*16 + l15)*4;
            f32x4 acc1[6];
            #pragma unroll
            for (int ot = 0; ot < 6; ++ot) acc1[ot] = (f32x4){0.f,0.f,0.f,0.f};

            {   // ks = 0 : rows quad*2, quad*2+1
                int ck0 = quad*2;
                frag_u f;
                f.p.lo = *(const bf16x4a*)&s_samp[ck0*SROWE + colb];
                f.p.hi = *(const bf16x4a*)&s_samp[(ck0+1)*SROWE + colb];
                #pragma unroll
                for (int ot = 0; ot < 6; ++ot)
                    acc1[ot] = __builtin_amdgcn_mfma_f32_16x16x32_bf16(
                        wfrag[0][ot], f.v, acc1[ot], 0, 0, 0);
            }
            {   // ks = 1 : rows 8+quad*2, 9+quad*2 (k 60..63 = zeros)
                int ck0 = 8 + quad*2;
                frag_u f;
                f.p.lo = *(const bf16x4a*)&s_samp[ck0*SROWE + colb];
                if (quad == 3) {
                    f.p.hi = (bf16x4a){};
                } else {
                    f.p.hi = *(const bf16x4a*)&s_samp[(ck0+1)*SROWE + colb];
                }
                #pragma unroll
                for (int ot = 0; ot < 6; ++ot)
                    acc1[ot] = __builtin_amdgcn_mfma_f32_16x16x32_bf16(
                        wfrag[1][ot], f.v, acc1[ot], 0, 0, 0);
            }

            // epilogue -> t1f fragment-major [kk(ka,icb)][a2l][q2][j]
            int pixel = pt*16 + l15;
            int a2l = pixel >> 2, ka = pixel & 3;
            #pragma unroll
            for (int ot = 0; ot < 6; ++ot) {
                f32x4 v = acc1[ot] + b1v[ot];
                bf16x4a wv;
                wv[0] = (__bf16)v[0]; wv[1] = (__bf16)v[1];
                wv[2] = (__bf16)v[2]; wv[3] = (__bf16)v[3];
                int icbase = ot*16 + quad*4;
                int icb = icbase >> 5;
                int q2  = (icbase >> 3) & 3;
                int jb  = icbase & 7;
                *(bf16x4a*)&t1f[(((ka*3 + icb)*32 + a2l)*4 + q2)*8 + jb] = wv;
            }
        }
        __syncthreads();   // B: t1f ready; s_samp reads done

        if (kr < 4) stage(kr + 1);   // prefetch overlaps conv2

        // ---- conv2 partial: wave's k-half = 6 k-steps
        #pragma unroll
        for (int ki = 0; ki < 6; ++ki) {
            int ka  = kp*2 + ki/3;
            int icb = ki % 3;
            int kk  = ka*3 + icb;
            int p   = kr*4 + ka;
            bf16x8 af = *(const bf16x8*)&t1f[((kk*32 + mt*16 + l15)*4 + quad)*8];
            const __bf16* wp = w2f + (size_t)((p*3 + icb)*6)*512 + lane*8;
            #pragma unroll
            for (int nt = 0; nt < 6; ++nt) {
                bf16x8 bf = *(const bf16x8*)(wp + nt*512);
                acc2[nt] = __builtin_amdgcn_mfma_f32_16x16x32_bf16(af, bf, acc2[nt], 0, 0, 0);
            }
        }
    }

    // ---- k-half reduction (red aliases s_samp)
    float* red = (float*)s_samp;     // [mt][16][97] fp32, 12416 B
    if (kp) {
        #pragma unroll
        for (int nt = 0; nt < 6; ++nt)
            #pragma unroll
            for (int r = 0; r < 4; ++r)
                red[mt*1552 + (quad*4 + r)*97 + nt*16 + l15] = acc2[nt][r];
    }
    __syncthreads();
    if (!kp) {
        size_t ob = ((size_t)b*1024 + r2*64 + ah*32 + mt*16)*ED;
        #pragma unroll
        for (int nt = 0; nt < 6; ++nt) {
            int oc = nt*16 + l15;
            float bias = b2[oc];
            #pragma unroll
            for (int r = 0; r < 4; ++r) {
                float v = acc2[nt][r] + red[mt*1552 + (quad*4 + r)*97 + oc] + bias;
                out[ob + (size_t)(quad*4 + r)*ED + oc] = v;
            }
        }
    }
}

extern "C" void kernel_launch(void* const* d_in, const int* in_sizes, int n_in,
                              void* d_out, int out_size, void* d_ws, size_t ws_size,
                              hipStream_t stream) {
    const float* x    = (const float*)d_in[0];
    const float* dist = (const float*)d_in[1];
    const float* w1   = (const float*)d_in[2];
    const float* b1   = (const float*)d_in[3];
    const float* w2   = (const float*)d_in[4];
    const float* b2   = (const float*)d_in[5];
    float* out = (float*)d_out;

    float* rtab   = (float*)d_ws;                 // 12800
    float* costab = rtab + NBATCH*NR;             // 1024
    float* sintab = costab + NA;                  // 1024
    __bf16* w2f   = (__bf16*)(sintab + NA);       // 184320 bf16
    __bf16* w1r   = w2f + ED*ED*20;               // 6144 bf16
    __bf16* xp    = w1r + ED*64;                  // 32*224*224*4 bf16
    __bf16* sp    = xp + (size_t)NBATCH*IMGSZ*IMGSZ*4;  // 32*3*400*1024 bf16

    float* theta_out = out + (size_t)NBATCH*1024*ED;

    prep_kernel<<<(ED*ED*20 + ED*64 + 255)/256, 256, 0, stream>>>(
        dist, w1, w2, rtab, costab, sintab, w2f, w1r, theta_out);
    pack_image_kernel<<<(NBATCH*IMGSZ*IMGSZ + 255)/256, 256, 0, stream>>>(x, xp);
    sample_kernel<<<dim3(NA/32, NR/16, NBATCH), 256, 0, stream>>>(
        xp, rtab, costab, sintab, sp);
    conv_fused_kernel<<<NBATCH*16*2, 256, 0, stream>>>(
        sp, w1r, w2f, b1, b2, out);
}